// Round 7
// baseline (135.648 us; speedup 1.0000x reference)
//
#include <hip/hip_runtime.h>
#include <stdint.h>

#define NDIM 64
#define KPOS 32
#define KNEG 64

// ds_swizzle BitMode: offset = (xor<<10) | (or<<5) | and
#define SWZI(x, pat) __builtin_amdgcn_ds_swizzle((int)(x), (pat))
#define SWZF(x, pat) __int_as_float(__builtin_amdgcn_ds_swizzle(__float_as_int(x), (pat)))

typedef unsigned int uint4v __attribute__((ext_vector_type(4)));

// u4 table: row = 32 bytes; byte b of row j = dims {2b (lo nibble), 2b+1 (hi)}; q = round(15*z)

// -------- Kernel 1: Zq4 = u4(sigmoid(P)), L_deg = MSE(Z@W_d, deg) ----------
__global__ __launch_bounds__(256) void pe_sig_deg_kernel(
    const float* __restrict__ P,
    const float* __restrict__ Wd,
    const float* __restrict__ deg,
    uint8_t* __restrict__ Zq,
    float* __restrict__ out,
    int N) {
  const int lane = threadIdx.x & 63;
  const int wid  = threadIdx.x >> 6;
  const int c1   = lane & 15;           // dim quad: dims [4c1, 4c1+4)
  const int sub  = lane >> 4;           // node within wave group (0..3)
  const int nwaves = (gridDim.x * blockDim.x) >> 6;
  const int gw = (blockIdx.x * blockDim.x + threadIdx.x) >> 6;

  const float4 w4 = *(const float4*)(Wd + 4 * c1);
  float acc = 0.f;
  for (int n0 = gw * 4; n0 < N; n0 += nwaves * 4) {
    const int n  = n0 + sub;
    const int nc = (n < N) ? n : (N - 1);
    const float4 p4 = *(const float4*)(P + (size_t)nc * NDIM + 4 * c1);
    const float z0 = 1.f / (1.f + __expf(-p4.x));
    const float z1 = 1.f / (1.f + __expf(-p4.y));
    const float z2 = 1.f / (1.f + __expf(-p4.z));
    const float z3 = 1.f / (1.f + __expf(-p4.w));
    const unsigned q = (unsigned)(z0 * 15.f + 0.5f)
                     | ((unsigned)(z1 * 15.f + 0.5f) << 4)
                     | ((unsigned)(z2 * 15.f + 0.5f) << 8)
                     | ((unsigned)(z3 * 15.f + 0.5f) << 12);
    *(unsigned short*)(Zq + (size_t)nc * 32 + 2 * c1) = (unsigned short)q;  // dup writes benign
    float dot = z0 * w4.x + z1 * w4.y + z2 * w4.z + z3 * w4.w;  // f32 path for L_deg
    dot += __shfl_xor(dot, 1); dot += __shfl_xor(dot, 2);
    dot += __shfl_xor(dot, 4); dot += __shfl_xor(dot, 8);
    const float dd = dot - deg[nc];
    acc += (n < N) ? dd * dd : 0.f;     // 16 duplicate lanes -> scale 1/16 at end
  }
  #pragma unroll
  for (int o = 1; o < 64; o <<= 1) acc += __shfl_xor(acc, o);
  __shared__ float sacc[4];
  if (lane == 0) sacc[wid] = acc;
  __syncthreads();
  if (threadIdx.x == 0)
    atomicAdd(out + 2, (sacc[0] + sacc[1] + sacc[2] + sacc[3]) * (1.f / (16.f * (float)N)));
}

// -------- nibble SAD helpers ----------------------------------------------
__device__ __forceinline__ unsigned sad8n(unsigned w, unsigned zl, unsigned zh, unsigned acc) {
  const unsigned M = 0x0F0F0F0Fu;
  acc = __builtin_amdgcn_sad_u8(w & M, zl, acc);
  acc = __builtin_amdgcn_sad_u8((w >> 4) & M, zh, acc);
  return acc;
}
__device__ __forceinline__ unsigned sad32n(uint4v w, uint4v zl, uint4v zh) {
  unsigned a = sad8n(w.x, zl.x, zh.x, 0u);
  a = sad8n(w.y, zl.y, zh.y, a);
  a = sad8n(w.z, zl.z, zh.z, a);
  a = sad8n(w.w, zl.w, zh.w, a);
  return a;
}

struct Idx6 { int p, na, nb, dp, dna, dnb; };

__device__ __forceinline__ Idx6 load_idx(
    const int* __restrict__ pos, const int* __restrict__ neg,
    const int* __restrict__ dpos, const int* __restrict__ dneg,
    int i, int N, int r) {
  const unsigned u = (unsigned)((i < N) ? i : (N - 1));
  Idx6 d;
  d.p   = pos [u * KPOS + r];
  d.na  = neg [u * KNEG + r];
  d.nb  = neg [u * KNEG + 32 + r];
  d.dp  = dpos[u * KPOS + r];
  d.dna = dneg[u * KNEG + r];
  d.dnb = dneg[u * KNEG + 32 + r];
  return d;
}

// -------- Kernel 2: both contrast losses (u4 rows, lane-pair per row) ------
__global__ __launch_bounds__(256) void pe_contrast_kernel(
    const uint8_t* __restrict__ Zq,
    const int* __restrict__ pos_idx,
    const int* __restrict__ neg_idx,
    const int* __restrict__ dpos_idx,
    const int* __restrict__ dneg_idx,
    float* __restrict__ out,
    int N) {
  const int lane = threadIdx.x & 63;
  const int r = lane >> 1;              // row slot 0..31
  const unsigned hoff = (unsigned)(lane & 1) << 4;   // 16B half of 32B row
  const int wid  = threadIdx.x >> 6;
  const int nw   = (gridDim.x * blockDim.x) >> 6;
  const int gw   = (blockIdx.x * blockDim.x + threadIdx.x) >> 6;

  #define NTROW(j) __builtin_nontemporal_load((const uint4v*)(Zq + (((size_t)(unsigned)(j)) << 5) + hoff))

  float l1 = 0.f, l2 = 0.f;
  unsigned pa1 = 0u, pa2 = 0u;
  const float S = 1.4426950408889634f / 15.f;   // log2(e)/15
  const unsigned M = 0x0F0F0F0Fu;

  int i = gw;
  Idx6 cur;
  if (i < N) cur = load_idx(pos_idx, neg_idx, dpos_idx, dneg_idx, i, N, r);
  while (i < N) {
    // ---- issue all 7 row-gathers up front ----
    const uint4v rz  = *(const uint4v*)(Zq + (((size_t)(unsigned)i) << 5) + hoff);
    const uint4v rp  = NTROW(cur.p);
    const uint4v rna = NTROW(cur.na);
    const uint4v rnb = NTROW(cur.nb);
    const uint4v rdp = NTROW(cur.dp);
    const uint4v rda = NTROW(cur.dna);
    const uint4v rdb = NTROW(cur.dnb);

    // ---- prefetch next node's indices ----
    const int inext = i + nw;
    Idx6 nxt = cur;
    if (inext < N) nxt = load_idx(pos_idx, neg_idx, dpos_idx, dneg_idx, inext, N, r);

    // ---- unpack zi nibbles ----
    const uint4v zl = rz & M;
    const uint4v zh = (rz >> 4) & M;

    // ---- positives: raw nibble-SAD accumulation (scaled once at end) ----
    pa1 += sad32n(rp,  zl, zh);
    pa2 += sad32n(rdp, zl, zh);

    // ---- negatives: per-row H via pair-sum, then LSE ----
    unsigned ha = sad32n(rna, zl, zh), hb = sad32n(rnb, zl, zh);
    unsigned ga = sad32n(rda, zl, zh), gb = sad32n(rdb, zl, zh);
    ha += (unsigned)SWZI(ha, 0x041F); hb += (unsigned)SWZI(hb, 0x041F);
    ga += (unsigned)SWZI(ga, 0x041F); gb += (unsigned)SWZI(gb, 0x041F);

    // H <= 960 -> exp2 arg <= 92.3, f32-safe without max-subtraction
    float e1 = exp2f((float)ha * S) + exp2f((float)hb * S);
    float e2 = exp2f((float)ga * S) + exp2f((float)gb * S);
    // butterfly over xors {2,4,8,16,32}: excludes xor-1, so each lane sums one
    // lane per pair -> every neighbor counted EXACTLY ONCE (no ln2 correction)
    e1 += SWZF(e1, 0x081F); e2 += SWZF(e2, 0x081F);
    e1 += SWZF(e1, 0x101F); e2 += SWZF(e2, 0x101F);
    e1 += SWZF(e1, 0x201F); e2 += SWZF(e2, 0x201F);
    e1 += SWZF(e1, 0x401F); e2 += SWZF(e2, 0x401F);
    e1 += __shfl_xor(e1, 32); e2 += __shfl_xor(e2, 32);
    l1 += __logf(e1);
    l2 += __logf(e2);

    i = inext;
    cur = nxt;
  }

  int p1s = (int)pa1, p2s = (int)pa2;
  #pragma unroll
  for (int o = 1; o < 64; o <<= 1) { p1s += __shfl_xor(p1s, o); p2s += __shfl_xor(p2s, o); }

  const float pscale = 1.f / (15.f * (float)KPOS);
  const float c1 = l1 - (float)p1s * pscale;     // sum_i (lse - mean_pos)
  const float c2 = l2 - (float)p2s * pscale;

  __shared__ float s1[4], s2[4];
  if (lane == 0) { s1[wid] = c1; s2[wid] = c2; }
  __syncthreads();
  if (threadIdx.x == 0) {
    atomicAdd(out + 0, s1[0] + s1[1] + s1[2] + s1[3]);
    atomicAdd(out + 1, s2[0] + s2[1] + s2[2] + s2[3]);
  }
  #undef NTROW
}

// -------- launch ------------------------------------------------------------
extern "C" void kernel_launch(void* const* d_in, const int* in_sizes, int n_in,
                              void* d_out, int out_size, void* d_ws, size_t ws_size,
                              hipStream_t stream) {
  const float* P       = (const float*)d_in[0];
  const float* Wd      = (const float*)d_in[1];
  const float* deg     = (const float*)d_in[2];
  const int*   pos_idx = (const int*)d_in[3];
  const int*   neg_idx = (const int*)d_in[4];
  const int*   dpos    = (const int*)d_in[5];
  const int*   dneg    = (const int*)d_in[6];
  float* out = (float*)d_out;

  const int N = in_sizes[2];            // deg_vec has N elements
  uint8_t* Zq = (uint8_t*)d_ws;         // N * 32 bytes = 1.6 MB (u4-packed)

  hipMemsetAsync(out, 0, (size_t)out_size * sizeof(float), stream);

  pe_sig_deg_kernel<<<1024, 256, 0, stream>>>(P, Wd, deg, Zq, out, N);
  pe_contrast_kernel<<<2048, 256, 0, stream>>>(Zq, pos_idx, neg_idx, dpos, dneg, out, N);
}

// Round 8
// 95.477 us; speedup vs baseline: 1.4207x; 1.4207x over previous
//
#include <hip/hip_runtime.h>
#include <stdint.h>

#define NDIM 64
#define KPOS 32
#define KNEG 64

// ds_swizzle BitMode: offset = (xor<<10) | (or<<5) | and
#define SWZI(x, pat) __builtin_amdgcn_ds_swizzle((int)(x), (pat))
#define SWZF(x, pat) __int_as_float(__builtin_amdgcn_ds_swizzle(__float_as_int(x), (pat)))

typedef unsigned int uint4v __attribute__((ext_vector_type(4)));

// u4 table: row = 32 bytes; byte b of row j = dims {2b (lo nibble), 2b+1 (hi)}; q = round(15*z)

// -------- Kernel 1: Zq4 = u4(sigmoid(P)), L_deg = MSE(Z@W_d, deg) ----------
__global__ __launch_bounds__(256) void pe_sig_deg_kernel(
    const float* __restrict__ P,
    const float* __restrict__ Wd,
    const float* __restrict__ deg,
    uint8_t* __restrict__ Zq,
    float* __restrict__ out,
    int N) {
  const int lane = threadIdx.x & 63;
  const int wid  = threadIdx.x >> 6;
  const int c1   = lane & 15;           // dim quad: dims [4c1, 4c1+4)
  const int sub  = lane >> 4;           // node within wave group (0..3)
  const int nwaves = (gridDim.x * blockDim.x) >> 6;
  const int gw = (blockIdx.x * blockDim.x + threadIdx.x) >> 6;

  const float4 w4 = *(const float4*)(Wd + 4 * c1);
  float acc = 0.f;
  for (int n0 = gw * 4; n0 < N; n0 += nwaves * 4) {
    const int n  = n0 + sub;
    const int nc = (n < N) ? n : (N - 1);
    const float4 p4 = *(const float4*)(P + (size_t)nc * NDIM + 4 * c1);
    const float z0 = 1.f / (1.f + __expf(-p4.x));
    const float z1 = 1.f / (1.f + __expf(-p4.y));
    const float z2 = 1.f / (1.f + __expf(-p4.z));
    const float z3 = 1.f / (1.f + __expf(-p4.w));
    const unsigned q = (unsigned)(z0 * 15.f + 0.5f)
                     | ((unsigned)(z1 * 15.f + 0.5f) << 4)
                     | ((unsigned)(z2 * 15.f + 0.5f) << 8)
                     | ((unsigned)(z3 * 15.f + 0.5f) << 12);
    *(unsigned short*)(Zq + (size_t)nc * 32 + 2 * c1) = (unsigned short)q;  // dup writes benign
    float dot = z0 * w4.x + z1 * w4.y + z2 * w4.z + z3 * w4.w;  // f32 path for L_deg
    dot += __shfl_xor(dot, 1); dot += __shfl_xor(dot, 2);
    dot += __shfl_xor(dot, 4); dot += __shfl_xor(dot, 8);
    const float dd = dot - deg[nc];
    acc += (n < N) ? dd * dd : 0.f;     // 16 duplicate lanes -> scale 1/16 at end
  }
  #pragma unroll
  for (int o = 1; o < 64; o <<= 1) acc += __shfl_xor(acc, o);
  __shared__ float sacc[4];
  if (lane == 0) sacc[wid] = acc;
  __syncthreads();
  if (threadIdx.x == 0)
    atomicAdd(out + 2, (sacc[0] + sacc[1] + sacc[2] + sacc[3]) * (1.f / (16.f * (float)N)));
}

// -------- nibble SAD helpers ----------------------------------------------
__device__ __forceinline__ unsigned sad8n(unsigned w, unsigned zl, unsigned zh, unsigned acc) {
  const unsigned M = 0x0F0F0F0Fu;
  acc = __builtin_amdgcn_sad_u8(w & M, zl, acc);
  acc = __builtin_amdgcn_sad_u8((w >> 4) & M, zh, acc);
  return acc;
}
__device__ __forceinline__ unsigned sad32n(uint4v w, uint4v zl, uint4v zh) {
  unsigned a = sad8n(w.x, zl.x, zh.x, 0u);
  a = sad8n(w.y, zl.y, zh.y, a);
  a = sad8n(w.z, zl.z, zh.z, a);
  a = sad8n(w.w, zl.w, zh.w, a);
  return a;
}

struct Idx6 { int p, na, nb, dp, dna, dnb; };

__device__ __forceinline__ Idx6 load_idx(
    const int* __restrict__ pos, const int* __restrict__ neg,
    const int* __restrict__ dpos, const int* __restrict__ dneg,
    int i, int N, int r) {
  const unsigned u = (unsigned)((i < N) ? i : (N - 1));
  Idx6 d;
  d.p   = pos [u * KPOS + r];
  d.na  = neg [u * KNEG + r];
  d.nb  = neg [u * KNEG + 32 + r];
  d.dp  = dpos[u * KPOS + r];
  d.dna = dneg[u * KNEG + r];
  d.dnb = dneg[u * KNEG + 32 + r];
  return d;
}

// -------- Kernel 2: both contrast losses (u4 rows, lane-pair per row) ------
__global__ __launch_bounds__(256) void pe_contrast_kernel(
    const uint8_t* __restrict__ Zq,
    const int* __restrict__ pos_idx,
    const int* __restrict__ neg_idx,
    const int* __restrict__ dpos_idx,
    const int* __restrict__ dneg_idx,
    float* __restrict__ out,
    int N) {
  const int lane = threadIdx.x & 63;
  const int r = lane >> 1;              // row slot 0..31
  const unsigned hoff = (unsigned)(lane & 1) << 4;   // 16B half of 32B row
  const int wid  = threadIdx.x >> 6;
  const int nw   = (gridDim.x * blockDim.x) >> 6;
  const int gw   = (blockIdx.x * blockDim.x + threadIdx.x) >> 6;

  // normal (cached) loads: Zq is 1.6 MB, L2-resident, re-read ~190x per row.
  // (round-7 lesson: nontemporal_load evicted it -> 70 MB extra HBM fetch)
  #define ZROW(j) (*(const uint4v*)(Zq + (((size_t)(unsigned)(j)) << 5) + hoff))

  float l1 = 0.f, l2 = 0.f;
  unsigned pa1 = 0u, pa2 = 0u;
  const float S = 1.4426950408889634f / 15.f;   // log2(e)/15
  const unsigned M = 0x0F0F0F0Fu;

  int i = gw;
  Idx6 cur;
  if (i < N) cur = load_idx(pos_idx, neg_idx, dpos_idx, dneg_idx, i, N, r);
  while (i < N) {
    // ---- issue all 7 row-gathers up front ----
    const uint4v rz  = ZROW(i);
    const uint4v rp  = ZROW(cur.p);
    const uint4v rna = ZROW(cur.na);
    const uint4v rnb = ZROW(cur.nb);
    const uint4v rdp = ZROW(cur.dp);
    const uint4v rda = ZROW(cur.dna);
    const uint4v rdb = ZROW(cur.dnb);

    // ---- prefetch next node's indices ----
    const int inext = i + nw;
    Idx6 nxt = cur;
    if (inext < N) nxt = load_idx(pos_idx, neg_idx, dpos_idx, dneg_idx, inext, N, r);

    // ---- unpack zi nibbles ----
    const uint4v zl = rz & M;
    const uint4v zh = (rz >> 4) & M;

    // ---- positives: raw nibble-SAD accumulation (scaled once at end) ----
    pa1 += sad32n(rp,  zl, zh);
    pa2 += sad32n(rdp, zl, zh);

    // ---- negatives: per-row H via pair-sum, then LSE ----
    unsigned ha = sad32n(rna, zl, zh), hb = sad32n(rnb, zl, zh);
    unsigned ga = sad32n(rda, zl, zh), gb = sad32n(rdb, zl, zh);
    ha += (unsigned)SWZI(ha, 0x041F); hb += (unsigned)SWZI(hb, 0x041F);
    ga += (unsigned)SWZI(ga, 0x041F); gb += (unsigned)SWZI(gb, 0x041F);

    // H <= 960 -> exp2 arg <= 92.3, f32-safe without max-subtraction
    float e1 = exp2f((float)ha * S) + exp2f((float)hb * S);
    float e2 = exp2f((float)ga * S) + exp2f((float)gb * S);
    // butterfly over xors {2,4,8,16,32}: excludes xor-1, so each lane sums one
    // lane per pair -> every neighbor counted EXACTLY ONCE (no ln2 correction)
    e1 += SWZF(e1, 0x081F); e2 += SWZF(e2, 0x081F);
    e1 += SWZF(e1, 0x101F); e2 += SWZF(e2, 0x101F);
    e1 += SWZF(e1, 0x201F); e2 += SWZF(e2, 0x201F);
    e1 += SWZF(e1, 0x401F); e2 += SWZF(e2, 0x401F);
    e1 += __shfl_xor(e1, 32); e2 += __shfl_xor(e2, 32);
    l1 += __logf(e1);
    l2 += __logf(e2);

    i = inext;
    cur = nxt;
  }

  int p1s = (int)pa1, p2s = (int)pa2;
  #pragma unroll
  for (int o = 1; o < 64; o <<= 1) { p1s += __shfl_xor(p1s, o); p2s += __shfl_xor(p2s, o); }

  const float pscale = 1.f / (15.f * (float)KPOS);
  const float c1 = l1 - (float)p1s * pscale;     // sum_i (lse - mean_pos)
  const float c2 = l2 - (float)p2s * pscale;

  __shared__ float s1[4], s2[4];
  if (lane == 0) { s1[wid] = c1; s2[wid] = c2; }
  __syncthreads();
  if (threadIdx.x == 0) {
    atomicAdd(out + 0, s1[0] + s1[1] + s1[2] + s1[3]);
    atomicAdd(out + 1, s2[0] + s2[1] + s2[2] + s2[3]);
  }
  #undef ZROW
}

// -------- launch ------------------------------------------------------------
extern "C" void kernel_launch(void* const* d_in, const int* in_sizes, int n_in,
                              void* d_out, int out_size, void* d_ws, size_t ws_size,
                              hipStream_t stream) {
  const float* P       = (const float*)d_in[0];
  const float* Wd      = (const float*)d_in[1];
  const float* deg     = (const float*)d_in[2];
  const int*   pos_idx = (const int*)d_in[3];
  const int*   neg_idx = (const int*)d_in[4];
  const int*   dpos    = (const int*)d_in[5];
  const int*   dneg    = (const int*)d_in[6];
  float* out = (float*)d_out;

  const int N = in_sizes[2];            // deg_vec has N elements
  uint8_t* Zq = (uint8_t*)d_ws;         // N * 32 bytes = 1.6 MB (u4-packed)

  hipMemsetAsync(out, 0, (size_t)out_size * sizeof(float), stream);

  pe_sig_deg_kernel<<<1024, 256, 0, stream>>>(P, Wd, deg, Zq, out, N);
  pe_contrast_kernel<<<2048, 256, 0, stream>>>(Zq, pos_idx, neg_idx, dpos, dneg, out, N);
}